// Round 1
// baseline (125.449 us; speedup 1.0000x reference)
//
#include <hip/hip_runtime.h>

#define NB 16    // batch
#define NN 64    // nodes
#define NFD 64   // node features
#define EFD 5    // edge types
#define AEFD 8   // attention edge types
#define MFD 64   // message features

#define ITILE 4
#define THREADS 256

__global__ __launch_bounds__(THREADS, 4)
void ggnn_msgpass_kernel(const float* __restrict__ afm,    // (B,N,NF)
                         const int*   __restrict__ bfm,    // (B,N,N)
                         const int*   __restrict__ a_bfm,  // (B,N)
                         const float* __restrict__ adj_w,  // (EF,MF,NF)
                         const float* __restrict__ adj_a,  // (AEF,MF)
                         const float* __restrict__ bias,   // (MF)
                         float* __restrict__ out)          // (B,N,MF)
{
    __shared__ float afm_s[NN][NFD];       // 16 KB
    __shared__ int   bfm_s[ITILE][NN];     // 1 KB
    __shared__ float S[ITILE][EFD][NFD];   // 5 KB

    const int t    = threadIdx.x;
    const int lane = t & 63;
    const int g    = t >> 6;               // wave id = which i in tile
    const int blk  = blockIdx.x;           // B * (N/ITILE) = 256 blocks
    const int b    = blk >> 4;             // 16 tiles per batch
    const int i0   = (blk & 15) * ITILE;
    const int i    = i0 + g;

    // ---- stage afm[b] (4096 floats) into LDS, coalesced float4 ----
    const float4* afm4   = (const float4*)(afm + (size_t)b * NN * NFD);
    float4*       afm_s4 = (float4*)&afm_s[0][0];
#pragma unroll
    for (int r = 0; r < 4; ++r)
        afm_s4[t + r * THREADS] = afm4[t + r * THREADS];

    // ---- stage 4 bfm rows (256 consecutive ints) ----
    bfm_s[g][lane] = bfm[(size_t)b * NN * NN + i0 * NN + t];

    __syncthreads();

    // ---- phase 2: bucket-sum S[g][e][n] = sum_{j: type==e+1} afm[b][j][n]
    // lane = n. Edge type is wave-uniform per j -> scalar branch chain.
    float a0 = 0.f, a1 = 0.f, a2 = 0.f, a3 = 0.f, a4 = 0.f;
#pragma unroll 4
    for (int j = 0; j < NN; ++j) {
        float v = afm_s[j][lane];
        int e = __builtin_amdgcn_readfirstlane(bfm_s[g][j]);
        if      (e == 1) a0 += v;
        else if (e == 2) a1 += v;
        else if (e == 3) a2 += v;
        else if (e == 4) a3 += v;
        else if (e == 5) a4 += v;
    }
    S[g][0][lane] = a0;
    S[g][1][lane] = a1;
    S[g][2][lane] = a2;
    S[g][3][lane] = a3;
    S[g][4][lane] = a4;

    __syncthreads();

    // ---- phase 3: msg[b][i][m] = sum_e W[e][m][:] . S[g][e][:]
    // lane = m. W rows read as float4 (L1/L2 resident); S reads are
    // uniform-address LDS broadcasts (free).
    const int m = lane;
    float o = 0.f;
#pragma unroll
    for (int e = 0; e < EFD; ++e) {
        const float4* wrow = (const float4*)(adj_w + ((size_t)e * MFD + m) * NFD);
        const float4* srow = (const float4*)&S[g][e][0];
#pragma unroll
        for (int n4 = 0; n4 < NFD / 4; ++n4) {
            float4 w = wrow[n4];
            float4 s = srow[n4];
            o += w.x * s.x + w.y * s.y + w.z * s.z + w.w * s.w;
        }
    }

    // ---- epilogue: attention scale + bias ----
    int a = a_bfm[b * NN + i];
    float att = (a > 0) ? adj_a[(a - 1) * MFD + m] : 0.f;
    out[((size_t)b * NN + i) * MFD + m] = o * att + bias[m];
}

extern "C" void kernel_launch(void* const* d_in, const int* in_sizes, int n_in,
                              void* d_out, int out_size, void* d_ws, size_t ws_size,
                              hipStream_t stream) {
    const float* afm   = (const float*)d_in[0];
    const int*   bfm   = (const int*)d_in[1];
    const int*   a_bfm = (const int*)d_in[2];
    const float* adj_w = (const float*)d_in[3];
    const float* adj_a = (const float*)d_in[4];
    const float* bias  = (const float*)d_in[5];
    float* out = (float*)d_out;

    dim3 grid(NB * (NN / ITILE));  // 256 blocks
    dim3 block(THREADS);
    ggnn_msgpass_kernel<<<grid, block, 0, stream>>>(afm, bfm, a_bfm, adj_w,
                                                    adj_a, bias, out);
}

// Round 2
// 86.981 us; speedup vs baseline: 1.4423x; 1.4423x over previous
//
#include <hip/hip_runtime.h>

#define NB 16    // batch
#define NN 64    // nodes
#define NFD 64   // node features
#define EFD 5    // edge types
#define MFD 64   // message features

#define ITILE 4
#define THREADS 256
#define WPAD 65  // padded W row stride in LDS: bank=(m+n)%32 -> 2 lanes/bank = free

__global__ __launch_bounds__(THREADS)
void ggnn_msgpass_kernel(const float* __restrict__ afm,    // (B,N,NF)
                         const int*   __restrict__ bfm,    // (B,N,N)
                         const int*   __restrict__ a_bfm,  // (B,N)
                         const float* __restrict__ adj_w,  // (EF,MF,NF)
                         const float* __restrict__ adj_a,  // (AEF,MF)
                         const float* __restrict__ bias,   // (MF)
                         float* __restrict__ out)          // (B,N,MF)
{
    __shared__ float afm_s[NN][NFD];            // 16 KB
    __shared__ int   bfm_s[ITILE][NN];          // 1 KB
    __shared__ float S[ITILE][EFD][NFD];        // 5 KB
    __shared__ float W_s[EFD * MFD][WPAD];      // 83.2 KB, row = e*64+m

    const int t    = threadIdx.x;
    const int lane = t & 63;
    const int g    = t >> 6;               // wave id = which i in tile
    const int blk  = blockIdx.x;           // 256 blocks
    const int b    = blk >> 4;
    const int i0   = (blk & 15) * ITILE;
    const int i    = i0 + g;

    // ---- stage afm[b] (16 KB) into LDS, coalesced float4 ----
    const float4* afm4   = (const float4*)(afm + (size_t)b * NN * NFD);
    float4*       afm_s4 = (float4*)&afm_s[0][0];
#pragma unroll
    for (int r = 0; r < 4; ++r)
        afm_s4[t + r * THREADS] = afm4[t + r * THREADS];

    // ---- stage W (80 KB) into LDS once per block, coalesced float4 reads,
    //      scattered-by-row padded writes (one-time cost) ----
    const float4* w4 = (const float4*)adj_w;
#pragma unroll
    for (int k = 0; k < 20; ++k) {
        int f4 = t + k * THREADS;          // float4 index, 5120 total
        float4 w = w4[f4];
        int row = f4 >> 4;                 // 16 float4 per 64-float row
        int n   = (f4 & 15) << 2;
        W_s[row][n]     = w.x;
        W_s[row][n + 1] = w.y;
        W_s[row][n + 2] = w.z;
        W_s[row][n + 3] = w.w;
    }

    // ---- stage 4 bfm rows (256 ints) ----
    bfm_s[g][lane] = bfm[(size_t)b * NN * NN + i0 * NN + t];

    __syncthreads();

    // ---- phase 2: bucket-sum S[g][e][n] = sum_{j: type==e+1} afm[b][j][n]
    // lane = n; edge type wave-uniform per j -> scalar branch chain.
    float a0 = 0.f, a1 = 0.f, a2 = 0.f, a3 = 0.f, a4 = 0.f;
#pragma unroll 4
    for (int j = 0; j < NN; ++j) {
        float v = afm_s[j][lane];
        int e = __builtin_amdgcn_readfirstlane(bfm_s[g][j]);
        if      (e == 1) a0 += v;
        else if (e == 2) a1 += v;
        else if (e == 3) a2 += v;
        else if (e == 4) a3 += v;
        else if (e == 5) a4 += v;
    }
    S[g][0][lane] = a0;
    S[g][1][lane] = a1;
    S[g][2][lane] = a2;
    S[g][3][lane] = a3;
    S[g][4][lane] = a4;

    __syncthreads();

    // ---- phase 3: msg[b][i][m] = sum_e W[e][m][:] . S[g][e][:]
    // lane = m. W from LDS (stride-65 pad => bank (m+n)%32, 2 lanes/bank,
    // conflict-free); S reads are uniform-address broadcasts.
    const int m = lane;
    float o = 0.f;
#pragma unroll
    for (int e = 0; e < EFD; ++e) {
        const float* wrow = W_s[e * MFD + m];
        const float* srow = S[g][e];
        float acc = 0.f;
#pragma unroll
        for (int n = 0; n < NFD; ++n)
            acc += wrow[n] * srow[n];
        o += acc;
    }

    // ---- epilogue: attention scale + bias ----
    int a = a_bfm[b * NN + i];
    float att = (a > 0) ? adj_a[(a - 1) * MFD + m] : 0.f;
    out[((size_t)b * NN + i) * MFD + m] = o * att + bias[m];
}

extern "C" void kernel_launch(void* const* d_in, const int* in_sizes, int n_in,
                              void* d_out, int out_size, void* d_ws, size_t ws_size,
                              hipStream_t stream) {
    const float* afm   = (const float*)d_in[0];
    const int*   bfm   = (const int*)d_in[1];
    const int*   a_bfm = (const int*)d_in[2];
    const float* adj_w = (const float*)d_in[3];
    const float* adj_a = (const float*)d_in[4];
    const float* bias  = (const float*)d_in[5];
    float* out = (float*)d_out;

    dim3 grid(NB * (NN / ITILE));  // 256 blocks
    dim3 block(THREADS);
    ggnn_msgpass_kernel<<<grid, block, 0, stream>>>(afm, bfm, a_bfm, adj_w,
                                                    adj_a, bias, out);
}